// Round 8
// baseline (110.815 us; speedup 1.0000x reference)
//
#include <hip/hip_runtime.h>

// PointNet++ set abstraction: ball query (first-16-by-index within r=0.5) +
// gather + rel-coords/feat concat + 2-layer MLP (leaky 0.1) + max-pool.
// B=4, N=16384, M=4096, K=16.
//
// Round 8: amortize the straggler full-scans.
//  - Queries with s=|q|^2 >= 5 (~17%) have <~44 hits; most scan nearly all
//    16384 points with no early exit possible. Batch 4 SAME-BATCH straggler
//    queries per wave: 1 point-load serves 4 dot tests -> 4x fewer waves,
//    4x less VMEM, ~2.3x less issue for ~60% of all pair work.
//  - Short queries: round-6 proven single-query scan, 5-bucket descending
//    order (longest first).
//  - MLP: round-6 LDS-weights version (round-7's global-weights regressed:
//    32 serialized vmcnt waits/query; LDS b128 issue is 4cyc + short lgkm).
//  - d2 and MLP arithmetic bit-identical to all passing rounds.

constexpr int N_PTS = 16384;
constexpr int M_Q   = 4096;
constexpr int KNN   = 16;
constexpr int TOTAL_Q = 4 * M_Q;     // 16384
constexpr int TOTAL_P = 4 * N_PTS;   // 65536
constexpr int NBKT   = 5;            // single-query buckets 0..4

// ---- ws layout ----
constexpr size_t WS_PKX   = 0;                                  // float4[65536] = 1MB
constexpr size_t WS_BKT   = WS_PKX + (size_t)TOTAL_P * 16;      // 5 x int[16384]
constexpr size_t WS_SLST  = WS_BKT + (size_t)NBKT * TOTAL_Q * 4;// 4 x int[4096]
constexpr size_t WS_CNTS  = WS_SLST + (size_t)4 * M_Q * 4;      // int[9]
constexpr size_t WS_NEED  = WS_CNTS + 64;

// ------- pre-pass: pack points + classify queries -------
__global__ __launch_bounds__(256) void prep_kernel(
    const float* __restrict__ xyz, const int* __restrict__ fps,
    float4* __restrict__ pkX, int* __restrict__ bkt,
    int* __restrict__ sLst, int* __restrict__ cnts)
{
    const int i = blockIdx.x * 256 + threadIdx.x;
    const int lane = threadIdx.x & 63;
    const unsigned long long lt_mask = (1ull << lane) - 1ull;

    // pack points: {x,y,z,|p|^2} with the reference-exact sq expression
    if (i < TOTAL_P) {
        const float x = xyz[i * 3 + 0], y = xyz[i * 3 + 1], z = xyz[i * 3 + 2];
        const float sq = __fadd_rn(__fadd_rn(__fmul_rn(x, x), __fmul_rn(y, y)),
                                   __fmul_rn(z, z));
        pkX[i] = make_float4(x, y, z, sq);
    }

    // classify queries; i < 16384 is wave-aligned, b uniform per wave
    if (i < TOTAL_Q) {
        const int b = i >> 12;
        const int pidx = fps[i];
        const size_t base3 = ((size_t)b * N_PTS + pidx) * 3;
        const float x = xyz[base3 + 0], y = xyz[base3 + 1], z = xyz[base3 + 2];
        const float s = __fadd_rn(__fadd_rn(__fmul_rn(x, x), __fmul_rn(y, y)),
                                  __fmul_rn(z, z));
        const bool isStrag = (s >= 5.0f);
        int key = (int)s;
        key = key > NBKT - 1 ? NBKT - 1 : key;   // 0..4 (s>=0 always)

        // straggler: per-b list, wave-aggregated
        {
            const unsigned long long mk = __ballot(isStrag);
            if (mk) {
                int base = 0;
                if (lane == 0) base = atomicAdd(&cnts[5 + b], (int)__popcll(mk));
                base = __shfl(base, 0, 64);
                if (isStrag) sLst[b * M_Q + base + __popcll(mk & lt_mask)] = i;
            }
        }
        // singles: 5 buckets, wave-aggregated
        #pragma unroll
        for (int bb = 0; bb < NBKT; ++bb) {
            const bool mine = (!isStrag) && (key == bb);
            const unsigned long long mk = __ballot(mine);
            if (mk) {
                int base = 0;
                if (lane == 0) base = atomicAdd(&cnts[bb], (int)__popcll(mk));
                base = __shfl(base, 0, 64);
                if (mine) bkt[bb * TOTAL_Q + base + __popcll(mk & lt_mask)] = i;
            }
        }
    }
}

// ---------------- shared MLP (LDS weights, round-6 proven) ----------------
__device__ __forceinline__ void run_mlp(
    int q, int b, int wave, int row, int lane,
    const float4* __restrict__ pX, const float* __restrict__ feat,
    float qx, float qy, float qz,
    const float* sW1, const float* sW2, const float* sb1, const float* sb2,
    int sNbr[4][4][KNN], float* __restrict__ out)
{
    const int k  = lane >> 2;
    const int co = (lane & 3) * 8;
    const int ni = sNbr[wave][row][k];

    const float4 gx = pX[ni];
    const size_t f3 = ((size_t)b * N_PTS + ni) * 3;
    const float in0 = gx.x - qx;
    const float in1 = gx.y - qy;
    const float in2 = gx.z - qz;
    const float in3 = feat[f3 + 0];
    const float in4 = feat[f3 + 1];
    const float in5 = feat[f3 + 2];

    float h1[8];
    #pragma unroll
    for (int i = 0; i < 8; ++i) {
        float a = sb1[co + i];
        a += in0 * sW1[0 * 32 + co + i];
        a += in1 * sW1[1 * 32 + co + i];
        a += in2 * sW1[2 * 32 + co + i];
        a += in3 * sW1[3 * 32 + co + i];
        a += in4 * sW1[4 * 32 + co + i];
        a += in5 * sW1[5 * 32 + co + i];
        h1[i] = (a >= 0.0f) ? a : 0.1f * a;
    }

    float h2[8];
    #pragma unroll
    for (int i = 0; i < 8; ++i) h2[i] = sb2[co + i];
    const int baseLane = lane & ~3;
    #pragma unroll
    for (int jj = 0; jj < 8; ++jj) {
        #pragma unroll
        for (int g = 0; g < 4; ++g) {
            const float v = __shfl(h1[jj], baseLane + g, 64);
            const int rr = g * 8 + jj;
            #pragma unroll
            for (int i = 0; i < 8; ++i)
                h2[i] += v * sW2[rr * 32 + co + i];
        }
    }

    #pragma unroll
    for (int i = 0; i < 8; ++i) {
        float v = h2[i];
        v = (v >= 0.0f) ? v : 0.1f * v;
        v = fmaxf(v, __shfl_xor(v, 4, 64));
        v = fmaxf(v, __shfl_xor(v, 8, 64));
        v = fmaxf(v, __shfl_xor(v, 16, 64));
        v = fmaxf(v, __shfl_xor(v, 32, 64));
        h2[i] = v;
    }

    if (k == 0) {
        float* op = out + (size_t)q * 32 + co;
        #pragma unroll
        for (int i = 0; i < 8; ++i) op[i] = h2[i];
    }
}

// ---------------- scan macros ----------------
#define LOAD8(R, P, P2)                                          \
    {                                                            \
        _Pragma("unroll")                                        \
        for (int j = 0; j < 4; ++j) R[j] = (P)[j * 64];          \
        _Pragma("unroll")                                        \
        for (int j = 0; j < 4; ++j) R[4 + j] = (P2)[j * 64];     \
    }

#define PROC8(R, CB)                                                          \
    {                                                                         \
        _Pragma("unroll")                                                     \
        for (int j = 0; j < 8; ++j) {                                         \
            float dot = __fmul_rn(qx, R[j].x);                                \
            dot = __builtin_fmaf(qy, R[j].y, dot);                            \
            dot = __builtin_fmaf(qz, R[j].z, dot);                            \
            const float d2 = __fsub_rn(__fadd_rn(sqq, R[j].w),                \
                                       __fmul_rn(2.0f, dot));                 \
            const bool hit = (d2 <= 0.25f);                                   \
            const unsigned long long mk = __ballot(hit);                      \
            if (hit) {                                                        \
                const int pos = count + __popcll(mk & lt_mask);               \
                if (pos < KNN) sNbr[wave][0][pos] = (CB) + j * 64 + lane;     \
            }                                                                 \
            count += (int)__popcll(mk);                                       \
        }                                                                     \
    }

#define PROC8B4(R, CB)                                                        \
    {                                                                         \
        _Pragma("unroll")                                                     \
        for (int j = 0; j < 8; ++j) {                                         \
            _Pragma("unroll")                                                 \
            for (int kq = 0; kq < 4; ++kq) {                                  \
                float dot = __fmul_rn(qx4[kq], R[j].x);                       \
                dot = __builtin_fmaf(qy4[kq], R[j].y, dot);                   \
                dot = __builtin_fmaf(qz4[kq], R[j].z, dot);                   \
                const float d2 = __fsub_rn(__fadd_rn(sqq4[kq], R[j].w),       \
                                           __fmul_rn(2.0f, dot));             \
                const bool hit = (d2 <= 0.25f);                               \
                const unsigned long long mk = __ballot(hit);                  \
                if (mk && cnt[kq] < KNN) {                                    \
                    if (hit) {                                                \
                        const int pos = cnt[kq] + __popcll(mk & lt_mask);     \
                        if (pos < KNN)                                        \
                            sNbr[wave][kq][pos] = (CB) + j * 64 + lane;       \
                    }                                                         \
                }                                                             \
                cnt[kq] += (int)__popcll(mk);                                 \
            }                                                                 \
        }                                                                     \
    }

// ---------------- main fused kernel ----------------
__global__ __launch_bounds__(256) void pe_flow_main_kernel(
    const float4* __restrict__ pkX, const float* __restrict__ feat,
    const int*   __restrict__ fps,
    const int*   __restrict__ bkt, const int* __restrict__ sLst,
    const int*   __restrict__ cnts,
    const float* __restrict__ W1, const float* __restrict__ b1,
    const float* __restrict__ W2, const float* __restrict__ b2,
    float* __restrict__ out)
{
    __shared__ float sW1[192];
    __shared__ float sW2[1024];
    __shared__ float sb1[32];
    __shared__ float sb2[32];
    __shared__ int   sNbr[4][4][KNN];

    const int tid = threadIdx.x;
    if (tid < 192) sW1[tid] = W1[tid];
    for (int i = tid; i < 1024; i += 256) sW2[i] = W2[i];
    if (tid < 32) { sb1[tid] = b1[tid]; sb2[tid] = b2[tid]; }
    __syncthreads();

    const int wave = tid >> 6;
    const int lane = tid & 63;
    const unsigned long long lt_mask = (1ull << lane) - 1ull;

    int c[9];
    #pragma unroll
    for (int t = 0; t < 9; ++t) c[t] = cnts[t];
    const int nSW = ((c[5] + 3) >> 2) + ((c[6] + 3) >> 2) +
                    ((c[7] + 3) >> 2) + ((c[8] + 3) >> 2);

    const int w = blockIdx.x * 4 + wave;

    if (w < nSW) {
        // ================= BATCH path: 4 stragglers, same b =================
        int u = w, bsel = 0, scSel = 0, found = 0;
        #pragma unroll
        for (int bb = 0; bb < 4; ++bb) {
            const int wb = (c[5 + bb] + 3) >> 2;
            if (!found) {
                if (u < wb) { bsel = bb; scSel = c[5 + bb]; found = 1; }
                else u -= wb;
            }
        }
        const int j0 = 4 * u;
        const int* list = sLst + bsel * M_Q;

        int qk[4]; bool val[4];
        #pragma unroll
        for (int kq = 0; kq < 4; ++kq) {
            const int j = j0 + kq;
            val[kq] = (j < scSel);
            qk[kq] = list[val[kq] ? j : j0];
        }

        const float4* pX = pkX + (size_t)bsel * N_PTS;
        float qx4[4], qy4[4], qz4[4], sqq4[4];
        #pragma unroll
        for (int kq = 0; kq < 4; ++kq) {
            const float4 Q = pX[fps[qk[kq]]];
            qx4[kq] = Q.x; qy4[kq] = Q.y; qz4[kq] = Q.z; sqq4[kq] = Q.w;
        }

        int cnt[4] = {0, 0, 0, 0};
        {
            const float4* pA  = pX + lane;
            const float4* pA2 = pA + 256;
            const float4* pB  = pA + 512;
            const float4* pB2 = pA + 768;
            float4 ra[8], rb[8];

            LOAD8(ra, pA, pA2);
            __builtin_amdgcn_sched_barrier(0);

            for (int base = 0; base < N_PTS; base += 1024) {
                LOAD8(rb, pB, pB2);
                __builtin_amdgcn_sched_barrier(0);
                PROC8B4(ra, base);
                if (cnt[0] >= KNN && cnt[1] >= KNN &&
                    cnt[2] >= KNN && cnt[3] >= KNN) break;

                pA += 1024; pA2 += 1024;
                if (base + 1024 < N_PTS) {
                    LOAD8(ra, pA, pA2);
                    __builtin_amdgcn_sched_barrier(0);
                }
                PROC8B4(rb, base + 512);
                if (cnt[0] >= KNN && cnt[1] >= KNN &&
                    cnt[2] >= KNN && cnt[3] >= KNN) break;
                pB += 1024; pB2 += 1024;
            }
        }

        #pragma unroll
        for (int r = 0; r < 4; ++r) {
            if (!val[r]) continue;                  // wave-uniform
            if (cnt[r] < KNN) {
                const int first = sNbr[wave][r][0]; // cnt>=1 (query itself)
                if (lane >= cnt[r] && lane < KNN) sNbr[wave][r][lane] = first;
            }
            run_mlp(qk[r], bsel, wave, r, lane, pX, feat,
                    qx4[r], qy4[r], qz4[r], sW1, sW2, sb1, sb2, sNbr, out);
        }
    } else {
        // ================= SINGLE path: round-6 proven scan =================
        const int i = w - nSW;
        int q = -1, off = 0;
        #pragma unroll
        for (int bb = NBKT - 1; bb >= 0; --bb) {
            const int cc = c[bb];
            const int idx = i - off;
            if (idx >= 0 && idx < cc) q = bkt[bb * TOTAL_Q + idx];
            off += cc;
        }
        if (q < 0) return;                          // idle tail wave
        const int b = q >> 12;

        const float4* pX = pkX + (size_t)b * N_PTS;
        const int pidx = fps[q];
        const float4 Q = pX[pidx];
        const float qx = Q.x, qy = Q.y, qz = Q.z, sqq = Q.w;

        int count = 0;
        {
            const float4* pA  = pX + lane;
            const float4* pA2 = pA + 256;
            const float4* pB  = pA + 512;
            const float4* pB2 = pA + 768;
            float4 ra[8], rb[8];

            LOAD8(ra, pA, pA2);
            __builtin_amdgcn_sched_barrier(0);

            for (int base = 0; base < N_PTS; base += 1024) {
                LOAD8(rb, pB, pB2);
                __builtin_amdgcn_sched_barrier(0);
                PROC8(ra, base);
                if (count >= KNN) break;            // wave-uniform

                pA += 1024; pA2 += 1024;
                if (base + 1024 < N_PTS) {
                    LOAD8(ra, pA, pA2);
                    __builtin_amdgcn_sched_barrier(0);
                }
                PROC8(rb, base + 512);
                if (count >= KNN) break;
                pB += 1024; pB2 += 1024;
            }
        }
        if (count < KNN) {
            const int first = sNbr[wave][0][0];     // count >= 1
            if (lane >= count && lane < KNN) sNbr[wave][0][lane] = first;
        }
        run_mlp(q, b, wave, 0, lane, pX, feat, qx, qy, qz,
                sW1, sW2, sb1, sb2, sNbr, out);
    }
}

// ---------------- round-1 fallback (self-contained, proven PASS) ----------------
__global__ __launch_bounds__(256) void pe_flow_fused_kernel(
    const float* __restrict__ xyz, const float* __restrict__ feat,
    const int* __restrict__ fps,
    const float* __restrict__ W1, const float* __restrict__ b1,
    const float* __restrict__ W2, const float* __restrict__ b2,
    float* __restrict__ out)
{
    __shared__ float sW1[192];
    __shared__ float sW2[1024];
    __shared__ float sb1[32];
    __shared__ float sb2[32];
    __shared__ int   sNbr[4][KNN];

    const int tid = threadIdx.x;
    if (tid < 192) sW1[tid] = W1[tid];
    for (int i = tid; i < 1024; i += 256) sW2[i] = W2[i];
    if (tid < 32) { sb1[tid] = b1[tid]; sb2[tid] = b2[tid]; }
    __syncthreads();

    const int wave = tid >> 6;
    const int lane = tid & 63;
    const int q = blockIdx.x * 4 + wave;
    const int b = q >> 12;
    const int m = q & (M_Q - 1);

    const float* xb = xyz  + (size_t)b * N_PTS * 3;
    const float* fb = feat + (size_t)b * N_PTS * 3;

    const int pidx = fps[b * M_Q + m];
    const float qx = xb[pidx * 3 + 0];
    const float qy = xb[pidx * 3 + 1];
    const float qz = xb[pidx * 3 + 2];
    const float sq_q = __fadd_rn(__fadd_rn(__fmul_rn(qx, qx), __fmul_rn(qy, qy)),
                                 __fmul_rn(qz, qz));

    int count = 0;
    const unsigned long long lt_mask = (1ull << lane) - 1ull;
    for (int base = 0; base < N_PTS; base += 64) {
        const int i = base + lane;
        const float px = xb[i * 3 + 0];
        const float py = xb[i * 3 + 1];
        const float pz = xb[i * 3 + 2];
        const float sq_p = __fadd_rn(__fadd_rn(__fmul_rn(px, px), __fmul_rn(py, py)),
                                     __fmul_rn(pz, pz));
        float dot = __fmul_rn(qx, px);
        dot = __builtin_fmaf(qy, py, dot);
        dot = __builtin_fmaf(qz, pz, dot);
        const float d2 = __fsub_rn(__fadd_rn(sq_q, sq_p), __fmul_rn(2.0f, dot));
        const bool hit = (d2 <= 0.25f);
        const unsigned long long mk = __ballot(hit);
        if (hit) {
            const int pos = count + __popcll(mk & lt_mask);
            if (pos < KNN) sNbr[wave][pos] = i;
        }
        count += (int)__popcll(mk);
        if (count >= KNN) break;
    }
    if (count < KNN) {
        const int first = sNbr[wave][0];
        if (lane >= count && lane < KNN) sNbr[wave][lane] = first;
    }

    const int k = lane >> 2;
    const int co = (lane & 3) * 8;
    const int ni = sNbr[wave][k];

    const float in0 = xb[ni * 3 + 0] - qx;
    const float in1 = xb[ni * 3 + 1] - qy;
    const float in2 = xb[ni * 3 + 2] - qz;
    const float in3 = fb[ni * 3 + 0];
    const float in4 = fb[ni * 3 + 1];
    const float in5 = fb[ni * 3 + 2];

    float h1[8];
    #pragma unroll
    for (int i = 0; i < 8; ++i) {
        float a = sb1[co + i];
        a += in0 * sW1[0 * 32 + co + i];
        a += in1 * sW1[1 * 32 + co + i];
        a += in2 * sW1[2 * 32 + co + i];
        a += in3 * sW1[3 * 32 + co + i];
        a += in4 * sW1[4 * 32 + co + i];
        a += in5 * sW1[5 * 32 + co + i];
        h1[i] = (a >= 0.0f) ? a : 0.1f * a;
    }

    float h2[8];
    #pragma unroll
    for (int i = 0; i < 8; ++i) h2[i] = sb2[co + i];
    const int baseLane = lane & ~3;
    #pragma unroll
    for (int jj = 0; jj < 8; ++jj) {
        #pragma unroll
        for (int g = 0; g < 4; ++g) {
            const float v = __shfl(h1[jj], baseLane + g, 64);
            const int row = g * 8 + jj;
            #pragma unroll
            for (int i = 0; i < 8; ++i)
                h2[i] += v * sW2[row * 32 + co + i];
        }
    }

    #pragma unroll
    for (int i = 0; i < 8; ++i) {
        float v = h2[i];
        v = (v >= 0.0f) ? v : 0.1f * v;
        v = fmaxf(v, __shfl_xor(v, 4, 64));
        v = fmaxf(v, __shfl_xor(v, 8, 64));
        v = fmaxf(v, __shfl_xor(v, 16, 64));
        v = fmaxf(v, __shfl_xor(v, 32, 64));
        h2[i] = v;
    }

    if (k == 0) {
        float* op = out + (size_t)q * 32 + co;
        #pragma unroll
        for (int i = 0; i < 8; ++i) op[i] = h2[i];
    }
}

extern "C" void kernel_launch(void* const* d_in, const int* in_sizes, int n_in,
                              void* d_out, int out_size, void* d_ws, size_t ws_size,
                              hipStream_t stream) {
    const float* xyz  = (const float*)d_in[0];
    const float* feat = (const float*)d_in[1];
    const int*   fps  = (const int*)d_in[2];
    const float* W1   = (const float*)d_in[3];
    const float* b1   = (const float*)d_in[4];
    const float* W2   = (const float*)d_in[5];
    const float* b2   = (const float*)d_in[6];
    float* out = (float*)d_out;

    if (ws_size < WS_NEED) {
        // fallback: proven round-1 kernel, no workspace needed
        pe_flow_fused_kernel<<<TOTAL_Q / 4, 256, 0, stream>>>(
            xyz, feat, fps, W1, b1, W2, b2, out);
        return;
    }

    char* ws = (char*)d_ws;
    float4* pkX = (float4*)(ws + WS_PKX);
    int* bkt    = (int*)(ws + WS_BKT);
    int* sLst   = (int*)(ws + WS_SLST);
    int* cnts   = (int*)(ws + WS_CNTS);

    hipMemsetAsync(cnts, 0, 64, stream);
    prep_kernel<<<TOTAL_P / 256, 256, 0, stream>>>(xyz, fps, pkX, bkt, sLst, cnts);
    pe_flow_main_kernel<<<TOTAL_Q / 4, 256, 0, stream>>>(
        pkX, feat, fps, bkt, sLst, cnts, W1, b1, W2, b2, out);
}

// Round 9
// 100.790 us; speedup vs baseline: 1.0995x; 1.0995x over previous
//
#include <hip/hip_runtime.h>

// PointNet++ set abstraction: ball query (first-16-by-index within r=0.5) +
// gather + rel-coords/feat concat + 2-layer MLP (leaky 0.1) + max-pool.
// B=4, N=16384, M=4096, K=16.
//
// Round 9: block-parallel straggler scans.
//  - Stragglers (s=|q|^2 >= 4, ~26%, scan >= ~13K pts): ONE BLOCK per query,
//    each of the 4 waves scans a 4096-pt segment (4 iters) into a private
//    LDS list; merge = concat of per-segment first-16 lists (segment k's
//    indices all precede segment k+1's). 4x shorter critical path, 4x more
//    waves in flight, zero extra pair tests (these scan everything anyway).
//  - Shorts: exact round-6 proven single-wave scan, 4-bucket longest-first.
//  - Round-8 lesson: NO multi-query batching (serializes 4x ballot work in
//    one wave). Round-7 lesson: weights stay in LDS.
//  - d2 / MLP arithmetic bit-identical to all passing rounds.

constexpr int N_PTS = 16384;
constexpr int M_Q   = 4096;
constexpr int KNN   = 16;
constexpr int TOTAL_Q = 4 * M_Q;     // 16384
constexpr int TOTAL_P = 4 * N_PTS;   // 65536

// ---- ws layout ----
constexpr size_t WS_PKX  = 0;                                // float4[65536] = 1MB
constexpr size_t WS_SLST = WS_PKX + (size_t)TOTAL_P * 16;    // int[16384]
constexpr size_t WS_BKT  = WS_SLST + (size_t)TOTAL_Q * 4;    // 4 x int[16384]
constexpr size_t WS_CNTS = WS_BKT + (size_t)4 * TOTAL_Q * 4; // int[5]
constexpr size_t WS_NEED = WS_CNTS + 64;

// ------- pre-pass: pack points + classify queries -------
__global__ __launch_bounds__(256) void prep_kernel(
    const float* __restrict__ xyz, const int* __restrict__ fps,
    float4* __restrict__ pkX, int* __restrict__ sLst,
    int* __restrict__ bkt, int* __restrict__ cnts)
{
    const int i = blockIdx.x * 256 + threadIdx.x;
    const int lane = threadIdx.x & 63;
    const unsigned long long lt_mask = (1ull << lane) - 1ull;

    // pack points: {x,y,z,|p|^2} with the reference-exact sq expression
    if (i < TOTAL_P) {
        const float x = xyz[i * 3 + 0], y = xyz[i * 3 + 1], z = xyz[i * 3 + 2];
        const float sq = __fadd_rn(__fadd_rn(__fmul_rn(x, x), __fmul_rn(y, y)),
                                   __fmul_rn(z, z));
        pkX[i] = make_float4(x, y, z, sq);
    }

    if (i < TOTAL_Q) {
        const int b = i >> 12;
        const int pidx = fps[i];
        const size_t base3 = ((size_t)b * N_PTS + pidx) * 3;
        const float x = xyz[base3 + 0], y = xyz[base3 + 1], z = xyz[base3 + 2];
        const float s = __fadd_rn(__fadd_rn(__fmul_rn(x, x), __fmul_rn(y, y)),
                                  __fmul_rn(z, z));
        const bool isStrag = (s >= 4.0f);   // scan >= ~13K pts, no early exit
        int key = (int)s;                    // 0..3 when !isStrag
        key = key > 3 ? 3 : key;

        // stragglers: single list, wave-aggregated append
        {
            const unsigned long long mk = __ballot(isStrag);
            if (mk) {
                int base = 0;
                if (lane == 0) base = atomicAdd(&cnts[4], (int)__popcll(mk));
                base = __shfl(base, 0, 64);
                if (isStrag) sLst[base + __popcll(mk & lt_mask)] = i;
            }
        }
        // shorts: 4 buckets by floor(s), wave-aggregated
        #pragma unroll
        for (int bb = 0; bb < 4; ++bb) {
            const bool mine = (!isStrag) && (key == bb);
            const unsigned long long mk = __ballot(mine);
            if (mk) {
                int base = 0;
                if (lane == 0) base = atomicAdd(&cnts[bb], (int)__popcll(mk));
                base = __shfl(base, 0, 64);
                if (mine) bkt[bb * TOTAL_Q + base + __popcll(mk & lt_mask)] = i;
            }
        }
    }
}

// ---------------- scan macros (round-6 proven) ----------------
#define LOAD8(R, P, P2)                                          \
    {                                                            \
        _Pragma("unroll")                                        \
        for (int j = 0; j < 4; ++j) R[j] = (P)[j * 64];          \
        _Pragma("unroll")                                        \
        for (int j = 0; j < 4; ++j) R[4 + j] = (P2)[j * 64];     \
    }

#define PROC8(R, CB, SD)                                                      \
    {                                                                         \
        _Pragma("unroll")                                                     \
        for (int j = 0; j < 8; ++j) {                                         \
            float dot = __fmul_rn(qx, R[j].x);                                \
            dot = __builtin_fmaf(qy, R[j].y, dot);                            \
            dot = __builtin_fmaf(qz, R[j].z, dot);                            \
            const float d2 = __fsub_rn(__fadd_rn(sqq, R[j].w),                \
                                       __fmul_rn(2.0f, dot));                 \
            const bool hit = (d2 <= 0.25f);                                   \
            const unsigned long long mk = __ballot(hit);                      \
            if (hit) {                                                        \
                const int pos = count + __popcll(mk & lt_mask);               \
                if (pos < KNN) (SD)[pos] = (CB) + j * 64 + lane;              \
            }                                                                 \
            count += (int)__popcll(mk);                                       \
        }                                                                     \
    }

// ---------------- MLP (LDS weights, round-6 proven math) ----------------
__device__ __forceinline__ void mlp_write(
    int q, int b, int ni, int lane,
    const float4* __restrict__ pX, const float* __restrict__ feat,
    float qx, float qy, float qz,
    const float* sW1, const float* sW2, const float* sb1, const float* sb2,
    float* __restrict__ out)
{
    const int k  = lane >> 2;
    const int co = (lane & 3) * 8;

    const float4 gx = pX[ni];
    const size_t f3 = ((size_t)b * N_PTS + ni) * 3;
    const float in0 = gx.x - qx;
    const float in1 = gx.y - qy;
    const float in2 = gx.z - qz;
    const float in3 = feat[f3 + 0];
    const float in4 = feat[f3 + 1];
    const float in5 = feat[f3 + 2];

    float h1[8];
    #pragma unroll
    for (int i = 0; i < 8; ++i) {
        float a = sb1[co + i];
        a += in0 * sW1[0 * 32 + co + i];
        a += in1 * sW1[1 * 32 + co + i];
        a += in2 * sW1[2 * 32 + co + i];
        a += in3 * sW1[3 * 32 + co + i];
        a += in4 * sW1[4 * 32 + co + i];
        a += in5 * sW1[5 * 32 + co + i];
        h1[i] = (a >= 0.0f) ? a : 0.1f * a;
    }

    float h2[8];
    #pragma unroll
    for (int i = 0; i < 8; ++i) h2[i] = sb2[co + i];
    const int baseLane = lane & ~3;
    #pragma unroll
    for (int jj = 0; jj < 8; ++jj) {
        #pragma unroll
        for (int g = 0; g < 4; ++g) {
            const float v = __shfl(h1[jj], baseLane + g, 64);
            const int rr = g * 8 + jj;
            #pragma unroll
            for (int i = 0; i < 8; ++i)
                h2[i] += v * sW2[rr * 32 + co + i];
        }
    }

    #pragma unroll
    for (int i = 0; i < 8; ++i) {
        float v = h2[i];
        v = (v >= 0.0f) ? v : 0.1f * v;
        v = fmaxf(v, __shfl_xor(v, 4, 64));
        v = fmaxf(v, __shfl_xor(v, 8, 64));
        v = fmaxf(v, __shfl_xor(v, 16, 64));
        v = fmaxf(v, __shfl_xor(v, 32, 64));
        h2[i] = v;
    }

    if (k == 0) {
        float* op = out + (size_t)q * 32 + co;
        #pragma unroll
        for (int i = 0; i < 8; ++i) op[i] = h2[i];
    }
}

// ---------------- main fused kernel ----------------
__global__ __launch_bounds__(256) void pe_flow_main_kernel(
    const float4* __restrict__ pkX, const float* __restrict__ feat,
    const int*   __restrict__ fps,
    const int*   __restrict__ sLst, const int* __restrict__ bkt,
    const int*   __restrict__ cnts,
    const float* __restrict__ W1, const float* __restrict__ b1,
    const float* __restrict__ W2, const float* __restrict__ b2,
    float* __restrict__ out)
{
    __shared__ float sW1[192];
    __shared__ float sW2[1024];
    __shared__ float sb1[32];
    __shared__ float sb2[32];
    __shared__ int   sSeg[4][KNN];
    __shared__ int   sCnt[4];

    const int tid  = threadIdx.x;
    const int wave = tid >> 6;
    const int lane = tid & 63;
    const unsigned long long lt_mask = (1ull << lane) - 1ull;

    int c[5];
    #pragma unroll
    for (int t = 0; t < 5; ++t) c[t] = cnts[t];
    const int nStrag = c[4];
    const int cShort = c[0] + c[1] + c[2] + c[3];
    const int nBlocks = nStrag + ((cShort + 3) >> 2);
    const int bid = blockIdx.x;
    if (bid >= nBlocks) return;          // whole block idle (uniform)

    // stage weights (before any divergent return)
    if (tid < 192) sW1[tid] = W1[tid];
    for (int i = tid; i < 1024; i += 256) sW2[i] = W2[i];
    if (tid < 32) { sb1[tid] = b1[tid]; sb2[tid] = b2[tid]; }
    __syncthreads();

    if (bid < nStrag) {
        // ========== STRAGGLER: one query per block, 4-way segment scan ======
        const int q = sLst[bid];
        const int b = q >> 12;
        const float4* pX = pkX + (size_t)b * N_PTS;
        const float4 Q = pX[fps[q]];
        const float qx = Q.x, qy = Q.y, qz = Q.z, sqq = Q.w;

        const int base0 = wave * 4096;   // this wave's segment
        int count = 0;
        {
            const float4* pA  = pX + base0 + lane;
            const float4* pA2 = pA + 256;
            const float4* pB  = pA + 512;
            const float4* pB2 = pA + 768;
            float4 ra[8], rb[8];

            LOAD8(ra, pA, pA2);
            __builtin_amdgcn_sched_barrier(0);

            for (int base = base0; base < base0 + 4096; base += 1024) {
                LOAD8(rb, pB, pB2);
                __builtin_amdgcn_sched_barrier(0);
                PROC8(ra, base, sSeg[wave]);
                if (count >= KNN) break;            // wave-uniform
                pA += 1024; pA2 += 1024;
                if (base + 1024 < base0 + 4096) {
                    LOAD8(ra, pA, pA2);
                    __builtin_amdgcn_sched_barrier(0);
                }
                PROC8(rb, base + 512, sSeg[wave]);
                if (count >= KNN) break;
                pB += 1024; pB2 += 1024;
            }
        }
        if (lane == 0) sCnt[wave] = count < KNN ? count : KNN;
        __syncthreads();
        if (wave != 0) return;

        // merge: segment k's indices all precede segment k+1's, so the
        // global first-16 is the first 16 of the concatenation.
        const int c0 = sCnt[0], c1 = sCnt[1], c2 = sCnt[2], c3 = sCnt[3];
        const int o1 = c0, o2 = o1 + c1, o3 = o2 + c2, tot = o3 + c3;
        const int t = lane >> 2;
        int ni;
        if (t < o1)       ni = sSeg[0][t];
        else if (t < o2)  ni = sSeg[1][t - o1];
        else if (t < o3)  ni = sSeg[2][t - o2];
        else if (t < tot) ni = sSeg[3][t - o3];
        else {            // pad with global first hit (tot >= 1: query itself)
            const int f = c0 ? 0 : (c1 ? 1 : (c2 ? 2 : 3));
            ni = sSeg[f][0];
        }
        mlp_write(q, b, ni, lane, pX, feat, qx, qy, qz,
                  sW1, sW2, sb1, sb2, out);
    } else {
        // ========== SHORT: round-6 proven single-wave path ==========
        const int i = (bid - nStrag) * 4 + wave;
        int q = -1, off = 0;
        #pragma unroll
        for (int bb = 3; bb >= 0; --bb) {       // longest buckets first
            const int cc = c[bb];
            const int idx = i - off;
            if (idx >= 0 && idx < cc) q = bkt[bb * TOTAL_Q + idx];
            off += cc;
        }
        if (q < 0) return;                      // idle tail wave (post-barrier)
        const int b = q >> 12;

        const float4* pX = pkX + (size_t)b * N_PTS;
        const float4 Q = pX[fps[q]];
        const float qx = Q.x, qy = Q.y, qz = Q.z, sqq = Q.w;

        int count = 0;
        {
            const float4* pA  = pX + lane;
            const float4* pA2 = pA + 256;
            const float4* pB  = pA + 512;
            const float4* pB2 = pA + 768;
            float4 ra[8], rb[8];

            LOAD8(ra, pA, pA2);
            __builtin_amdgcn_sched_barrier(0);

            for (int base = 0; base < N_PTS; base += 1024) {
                LOAD8(rb, pB, pB2);
                __builtin_amdgcn_sched_barrier(0);
                PROC8(ra, base, sSeg[wave]);
                if (count >= KNN) break;            // wave-uniform
                pA += 1024; pA2 += 1024;
                if (base + 1024 < N_PTS) {
                    LOAD8(ra, pA, pA2);
                    __builtin_amdgcn_sched_barrier(0);
                }
                PROC8(rb, base + 512, sSeg[wave]);
                if (count >= KNN) break;
                pB += 1024; pB2 += 1024;
            }
        }
        if (count < KNN) {
            const int first = sSeg[wave][0];        // count >= 1 (query itself)
            if (lane >= count && lane < KNN) sSeg[wave][lane] = first;
        }
        const int ni = sSeg[wave][lane >> 2];
        mlp_write(q, b, ni, lane, pX, feat, qx, qy, qz,
                  sW1, sW2, sb1, sb2, out);
    }
}

// ---------------- round-1 fallback (self-contained, proven PASS) ----------------
__global__ __launch_bounds__(256) void pe_flow_fused_kernel(
    const float* __restrict__ xyz, const float* __restrict__ feat,
    const int* __restrict__ fps,
    const float* __restrict__ W1, const float* __restrict__ b1,
    const float* __restrict__ W2, const float* __restrict__ b2,
    float* __restrict__ out)
{
    __shared__ float sW1[192];
    __shared__ float sW2[1024];
    __shared__ float sb1[32];
    __shared__ float sb2[32];
    __shared__ int   sNbr[4][KNN];

    const int tid = threadIdx.x;
    if (tid < 192) sW1[tid] = W1[tid];
    for (int i = tid; i < 1024; i += 256) sW2[i] = W2[i];
    if (tid < 32) { sb1[tid] = b1[tid]; sb2[tid] = b2[tid]; }
    __syncthreads();

    const int wave = tid >> 6;
    const int lane = tid & 63;
    const int q = blockIdx.x * 4 + wave;
    const int b = q >> 12;
    const int m = q & (M_Q - 1);

    const float* xb = xyz  + (size_t)b * N_PTS * 3;
    const float* fb = feat + (size_t)b * N_PTS * 3;

    const int pidx = fps[b * M_Q + m];
    const float qx = xb[pidx * 3 + 0];
    const float qy = xb[pidx * 3 + 1];
    const float qz = xb[pidx * 3 + 2];
    const float sq_q = __fadd_rn(__fadd_rn(__fmul_rn(qx, qx), __fmul_rn(qy, qy)),
                                 __fmul_rn(qz, qz));

    int count = 0;
    const unsigned long long lt_mask = (1ull << lane) - 1ull;
    for (int base = 0; base < N_PTS; base += 64) {
        const int i = base + lane;
        const float px = xb[i * 3 + 0];
        const float py = xb[i * 3 + 1];
        const float pz = xb[i * 3 + 2];
        const float sq_p = __fadd_rn(__fadd_rn(__fmul_rn(px, px), __fmul_rn(py, py)),
                                     __fmul_rn(pz, pz));
        float dot = __fmul_rn(qx, px);
        dot = __builtin_fmaf(qy, py, dot);
        dot = __builtin_fmaf(qz, pz, dot);
        const float d2 = __fsub_rn(__fadd_rn(sq_q, sq_p), __fmul_rn(2.0f, dot));
        const bool hit = (d2 <= 0.25f);
        const unsigned long long mk = __ballot(hit);
        if (hit) {
            const int pos = count + __popcll(mk & lt_mask);
            if (pos < KNN) sNbr[wave][pos] = i;
        }
        count += (int)__popcll(mk);
        if (count >= KNN) break;
    }
    if (count < KNN) {
        const int first = sNbr[wave][0];
        if (lane >= count && lane < KNN) sNbr[wave][lane] = first;
    }

    const int k = lane >> 2;
    const int co = (lane & 3) * 8;
    const int ni = sNbr[wave][k];

    const float in0 = xb[ni * 3 + 0] - qx;
    const float in1 = xb[ni * 3 + 1] - qy;
    const float in2 = xb[ni * 3 + 2] - qz;
    const float in3 = fb[ni * 3 + 0];
    const float in4 = fb[ni * 3 + 1];
    const float in5 = fb[ni * 3 + 2];

    float h1[8];
    #pragma unroll
    for (int i = 0; i < 8; ++i) {
        float a = sb1[co + i];
        a += in0 * sW1[0 * 32 + co + i];
        a += in1 * sW1[1 * 32 + co + i];
        a += in2 * sW1[2 * 32 + co + i];
        a += in3 * sW1[3 * 32 + co + i];
        a += in4 * sW1[4 * 32 + co + i];
        a += in5 * sW1[5 * 32 + co + i];
        h1[i] = (a >= 0.0f) ? a : 0.1f * a;
    }

    float h2[8];
    #pragma unroll
    for (int i = 0; i < 8; ++i) h2[i] = sb2[co + i];
    const int baseLane = lane & ~3;
    #pragma unroll
    for (int jj = 0; jj < 8; ++jj) {
        #pragma unroll
        for (int g = 0; g < 4; ++g) {
            const float v = __shfl(h1[jj], baseLane + g, 64);
            const int row = g * 8 + jj;
            #pragma unroll
            for (int i = 0; i < 8; ++i)
                h2[i] += v * sW2[row * 32 + co + i];
        }
    }

    #pragma unroll
    for (int i = 0; i < 8; ++i) {
        float v = h2[i];
        v = (v >= 0.0f) ? v : 0.1f * v;
        v = fmaxf(v, __shfl_xor(v, 4, 64));
        v = fmaxf(v, __shfl_xor(v, 8, 64));
        v = fmaxf(v, __shfl_xor(v, 16, 64));
        v = fmaxf(v, __shfl_xor(v, 32, 64));
        h2[i] = v;
    }

    if (k == 0) {
        float* op = out + (size_t)q * 32 + co;
        #pragma unroll
        for (int i = 0; i < 8; ++i) op[i] = h2[i];
    }
}

extern "C" void kernel_launch(void* const* d_in, const int* in_sizes, int n_in,
                              void* d_out, int out_size, void* d_ws, size_t ws_size,
                              hipStream_t stream) {
    const float* xyz  = (const float*)d_in[0];
    const float* feat = (const float*)d_in[1];
    const int*   fps  = (const int*)d_in[2];
    const float* W1   = (const float*)d_in[3];
    const float* b1   = (const float*)d_in[4];
    const float* W2   = (const float*)d_in[5];
    const float* b2   = (const float*)d_in[6];
    float* out = (float*)d_out;

    if (ws_size < WS_NEED) {
        // fallback: proven round-1 kernel, no workspace needed
        pe_flow_fused_kernel<<<TOTAL_Q / 4, 256, 0, stream>>>(
            xyz, feat, fps, W1, b1, W2, b2, out);
        return;
    }

    char* ws = (char*)d_ws;
    float4* pkX = (float4*)(ws + WS_PKX);
    int* sLst   = (int*)(ws + WS_SLST);
    int* bkt    = (int*)(ws + WS_BKT);
    int* cnts   = (int*)(ws + WS_CNTS);

    hipMemsetAsync(cnts, 0, 64, stream);
    prep_kernel<<<TOTAL_P / 256, 256, 0, stream>>>(xyz, fps, pkX, sLst, bkt, cnts);
    pe_flow_main_kernel<<<TOTAL_Q, 256, 0, stream>>>(
        pkX, feat, fps, sLst, bkt, cnts, W1, b1, W2, b2, out);
}